// Round 11
// baseline (293.825 us; speedup 1.0000x reference)
//
#include <hip/hip_runtime.h>
#include <hip/hip_bf16.h>
#include <math.h>

// B=2, S=2048, D=1024, H=16, HD=64. Inputs fp32, output fp32.
// R11 flash: O^T = V^T . P^T trick -> P^T (QK's C-layout) is DIRECTLY a
// B-operand with zero-padded upper k-slots: no LDS at all, no P round-trip,
// no alpha-broadcast shfls (O^T cols = q = l15 -> alpha/inv_l in-lane).
// Dual-stream paired q-groups at wave granularity: 2048 single-wave blocks,
// XCD-swizzled, longest-first. GEMMs unchanged (m97-style bf16 MFMA).

#define Bdim  2
#define Sdim  2048
#define Ddim  1024
#define Hn    16
#define HDdim 64
#define Mdim  (Bdim * Sdim)   // 4096

typedef unsigned short ushort_t;
typedef __attribute__((ext_vector_type(8))) short bfrag;   // 8 bf16 (4 VGPR)
typedef __attribute__((ext_vector_type(4))) float f4;

__device__ __forceinline__ ushort_t f2bf(float f) {
    union { float f; unsigned int i; } c;
    c.f = f;
    unsigned int x = c.i;
    unsigned int r = (x + 0x7fffu + ((x >> 16) & 1u)) >> 16;  // RNE
    return (ushort_t)r;
}
__device__ __forceinline__ unsigned int pk2bf(float a, float b) {
    return (unsigned int)f2bf(a) | ((unsigned int)f2bf(b) << 16);
}

__device__ __forceinline__ void glds16(const void* g, void* l) {
    __builtin_amdgcn_global_load_lds(
        (const __attribute__((address_space(1))) unsigned int*)g,
        (__attribute__((address_space(3))) unsigned int*)l, 16, 0, 0);
}

// ---------------- cast x: fp32 [M][K] -> bf16 same layout ----------------
__global__ __launch_bounds__(256)
void cast_x(const float* __restrict__ x, ushort_t* __restrict__ xb)
{
    size_t i = ((size_t)blockIdx.x * 256 + threadIdx.x) * 8;
    float4 a = *(const float4*)(x + i);
    float4 b = *(const float4*)(x + i + 4);
    ushort_t o[8] = {f2bf(a.x), f2bf(a.y), f2bf(a.z), f2bf(a.w),
                     f2bf(b.x), f2bf(b.y), f2bf(b.z), f2bf(b.w)};
    *(bfrag*)(xb + i) = *(const bfrag*)o;
}

// ------------- transpose-cast weights: W[k][n] fp32 -> Wt[n][k] bf16 -------
__global__ __launch_bounds__(256)
void wtrans(const float* __restrict__ W0, const float* __restrict__ W1,
            const float* __restrict__ W2, const float* __restrict__ W3,
            ushort_t* __restrict__ qkvT, ushort_t* __restrict__ oT)
{
    __shared__ ushort_t t[64][72];   // [n][k], padded
    const int tid = threadIdx.x;
    const int z = blockIdx.z;
    const float* W = (z == 0) ? W0 : (z == 1) ? W1 : (z == 2) ? W2 : W3;
    const int k0 = blockIdx.y * 64, n0 = blockIdx.x * 64;

    const int r = tid >> 4, c4 = (tid & 15) * 4;
    #pragma unroll
    for (int rr = 0; rr < 4; ++rr) {
        int k = r + rr * 16;
        float4 v = *(const float4*)&W[(size_t)(k0 + k) * Ddim + n0 + c4];
        t[c4 + 0][k] = f2bf(v.x);
        t[c4 + 1][k] = f2bf(v.y);
        t[c4 + 2][k] = f2bf(v.z);
        t[c4 + 3][k] = f2bf(v.w);
    }
    __syncthreads();
    ushort_t* out = (z < 3) ? (qkvT + (size_t)z * Ddim * Ddim) : oT;
    const int n = tid >> 2, kc = (tid & 3) * 16;
    *(bfrag*)&out[(size_t)(n0 + n) * Ddim + k0 + kc] = *(const bfrag*)&t[n][kc];
    *(bfrag*)&out[(size_t)(n0 + n) * Ddim + k0 + kc + 8] = *(const bfrag*)&t[n][kc + 8];
}

// ---------------- MFMA GEMM (m97 structure, NT) ----------------
// MODE 0: Ntot=3072 fused QKV; scatter bf16 to Q,K [B,H,S,HD], Vt [B,H,HD,S].
// MODE 1: Ntot=1024; fp32 out [M,N].
template <int MODE>
__global__ __launch_bounds__(256)
void gemm_mfma(const ushort_t* __restrict__ A, const ushort_t* __restrict__ Bt,
               const float* __restrict__ bQ, const float* __restrict__ bK,
               const float* __restrict__ bV,
               ushort_t* __restrict__ oQ, ushort_t* __restrict__ oK,
               ushort_t* __restrict__ oVt, float* __restrict__ oF)
{
    __shared__ ushort_t As[128 * 32];   // [row][k], 64 B rows
    __shared__ ushort_t Bs[128 * 32];

    const int tid  = threadIdx.x;
    const int lane = tid & 63;
    const int w    = tid >> 6;
    const int l15  = lane & 15;
    const int quad = lane >> 4;
    const int wr   = w >> 1, wc = w & 1;
    const int m0 = blockIdx.y * 128;
    const int n0 = blockIdx.x * 128;

    f4 acc[4][4];
    #pragma unroll
    for (int i = 0; i < 4; ++i)
        #pragma unroll
        for (int j = 0; j < 4; ++j) acc[i][j] = (f4){0.f, 0.f, 0.f, 0.f};

    const int srow  = w * 32 + (lane >> 2);
    const int selem = (lane & 3) * 8;
    const ushort_t* gA = A  + (size_t)(m0 + srow) * Ddim + selem;
    const ushort_t* gB = Bt + (size_t)(n0 + srow) * Ddim + selem;
    char* lA0 = (char*)As + (w * 32) * 64;
    char* lB0 = (char*)Bs + (w * 32) * 64;

    for (int kk = 0; kk < Ddim; kk += 32) {
        __syncthreads();
        glds16(gA + kk,              lA0);
        glds16(gA + 16 * Ddim + kk,  lA0 + 1024);
        glds16(gB + kk,              lB0);
        glds16(gB + 16 * Ddim + kk,  lB0 + 1024);
        __syncthreads();

        bfrag Af[4], Bf[4];
        #pragma unroll
        for (int i = 0; i < 4; ++i)
            Af[i] = *(const bfrag*)&As[(wr * 64 + i * 16 + l15) * 32 + quad * 8];
        #pragma unroll
        for (int j = 0; j < 4; ++j)
            Bf[j] = *(const bfrag*)&Bs[(wc * 64 + j * 16 + l15) * 32 + quad * 8];
        #pragma unroll
        for (int i = 0; i < 4; ++i)
            #pragma unroll
            for (int j = 0; j < 4; ++j)
                acc[i][j] = __builtin_amdgcn_mfma_f32_16x16x32_bf16(Af[i], Bf[j], acc[i][j], 0, 0, 0);
    }

    if constexpr (MODE == 0) {
        const int sel   = n0 >> 10;
        const int dbase = n0 & 1023;
        const float* bias = (sel == 0) ? bQ : (sel == 1) ? bK : bV;
        ushort_t* dst = (sel == 0) ? oQ : (sel == 1) ? oK : oVt;
        #pragma unroll
        for (int j = 0; j < 4; ++j) {
            int dn = dbase + wc * 64 + j * 16 + l15;
            float bv = bias[dn];
            int h = dn >> 6, e = dn & 63;
            #pragma unroll
            for (int i = 0; i < 4; ++i) {
                #pragma unroll
                for (int r = 0; r < 4; ++r) {
                    int m = m0 + wr * 64 + i * 16 + quad * 4 + r;
                    int b = m >> 11, s = m & 2047;
                    float v = acc[i][j][r] + bv;
                    if (sel < 2)
                        dst[((((size_t)b * Hn + h) * Sdim + s) << 6) + e] = f2bf(v);
                    else
                        dst[(((size_t)b * Hn + h) * HDdim + e) * Sdim + s] = f2bf(v);
                }
            }
        }
    } else {
        #pragma unroll
        for (int j = 0; j < 4; ++j) {
            int n = n0 + wc * 64 + j * 16 + l15;
            float bv = bQ[n];   // bo
            #pragma unroll
            for (int i = 0; i < 4; ++i)
                #pragma unroll
                for (int r = 0; r < 4; ++r) {
                    int m = m0 + wr * 64 + i * 16 + quad * 4 + r;
                    oF[(size_t)m * Ddim + n] = acc[i][j][r] + bv;
                }
        }
    }
}

// -------- Flash attention: O^T trick, no LDS, dual-stream, 1 wave/block ----
#define FA_BK 32

__global__ __launch_bounds__(64)
void flash_mfma(const ushort_t* __restrict__ Q, const ushort_t* __restrict__ K,
                const ushort_t* __restrict__ Vt, ushort_t* __restrict__ ctx)
{
    const int lane = threadIdx.x;
    const int l15  = lane & 15;
    const int quad = lane >> 4;
    // 2048 blocks: bh swizzle (4 bh per XCD slot), pair g asc = longest-first
    const int bidx = blockIdx.x;
    const int bh   = (bidx & 7) * 4 + ((bidx >> 3) & 3);
    const int g    = bidx >> 5;             // 0..63
    const int qwA  = g * 16;                // short stream
    const int qwB  = (127 - g) * 16;        // long stream
    const float scale = 0.125f;

    const ushort_t* Kp = K  + (size_t)bh * Sdim * HDdim;
    const ushort_t* Vp = Vt + (size_t)bh * HDdim * Sdim;

    const ushort_t* QrA = Q + ((size_t)bh * Sdim + qwA + l15) * HDdim;
    const ushort_t* QrB = Q + ((size_t)bh * Sdim + qwB + l15) * HDdim;
    bfrag QA0 = *(const bfrag*)(QrA + quad * 8);
    bfrag QA1 = *(const bfrag*)(QrA + 32 + quad * 8);
    bfrag QB0 = *(const bfrag*)(QrB + quad * 8);
    bfrag QB1 = *(const bfrag*)(QrB + 32 + quad * 8);

    f4 OTA[4], OTB[4];
    #pragma unroll
    for (int c = 0; c < 4; ++c) { OTA[c] = (f4){0.f,0.f,0.f,0.f}; OTB[c] = (f4){0.f,0.f,0.f,0.f}; }
    float mA = -INFINITY, lA = 0.f, mB = -INFINITY, lB = 0.f;

    const int ntA = (qwA + 47) >> 5;
    const int ntB = (qwB + 47) >> 5;

    bfrag Kc[4], Kn[4];
    uint2 Vc[8], Vn[8];

    auto loadTile = [&](int k0, bfrag (&Kf)[4], uint2 (&Vf)[8]) {
        #pragma unroll
        for (int h = 0; h < 2; ++h) {
            const ushort_t* kr = Kp + (size_t)(k0 + h * 16 + l15) * HDdim;
            Kf[h * 2]     = *(const bfrag*)(kr + quad * 8);
            Kf[h * 2 + 1] = *(const bfrag*)(kr + 32 + quad * 8);
        }
        #pragma unroll
        for (int c = 0; c < 4; ++c)
            #pragma unroll
            for (int h = 0; h < 2; ++h)
                Vf[c * 2 + h] = *(const uint2*)(Vp + (size_t)(c * 16 + l15) * Sdim
                                                + k0 + h * 16 + quad * 4);
    };

    // one stream, one 32-key tile. P^T stays in-lane: C-layout row=key=quad*4+r
    // maps to virtual B k-slots quad*8+j (upper 4 zero); V^T frag = A-operand.
    auto streamTile = [&](int k0, int qw, bfrag Qf0, bfrag Qf1,
                          bfrag (&Kf)[4], uint2 (&Vf)[8],
                          f4 (&OT)[4], float& m_prev, float& l_part) {
        f4 ST0 = (f4){0.f,0.f,0.f,0.f}, ST1 = (f4){0.f,0.f,0.f,0.f};
        ST0 = __builtin_amdgcn_mfma_f32_16x16x32_bf16(Kf[0], Qf0, ST0, 0, 0, 0);
        ST0 = __builtin_amdgcn_mfma_f32_16x16x32_bf16(Kf[1], Qf1, ST0, 0, 0, 0);
        ST1 = __builtin_amdgcn_mfma_f32_16x16x32_bf16(Kf[2], Qf0, ST1, 0, 0, 0);
        ST1 = __builtin_amdgcn_mfma_f32_16x16x32_bf16(Kf[3], Qf1, ST1, 0, 0, 0);

        float p0[4], p1[4];
        float mt = -INFINITY;
        if (k0 + FA_BK - 1 <= qw) {        // fully valid
            #pragma unroll
            for (int r = 0; r < 4; ++r) {
                p0[r] = ST0[r] * scale;
                p1[r] = ST1[r] * scale;
                mt = fmaxf(mt, fmaxf(p0[r], p1[r]));
            }
        } else {                            // diagonal: causal mask
            const int q_g = qw + l15;
            #pragma unroll
            for (int r = 0; r < 4; ++r) {
                int ka = k0 + quad * 4 + r;
                int kb = ka + 16;
                p0[r] = (ka <= q_g) ? ST0[r] * scale : -INFINITY;
                p1[r] = (kb <= q_g) ? ST1[r] * scale : -INFINITY;
                mt = fmaxf(mt, fmaxf(p0[r], p1[r]));
            }
        }
        mt = fmaxf(mt, __shfl_xor(mt, 16, 64));
        mt = fmaxf(mt, __shfl_xor(mt, 32, 64));
        float m_new = fmaxf(m_prev, mt);
        float alpha = __expf(m_prev - m_new);    // first tile: exp(-inf)=0
        float ls = 0.f;
        #pragma unroll
        for (int r = 0; r < 4; ++r) {
            p0[r] = __expf(p0[r] - m_new);       // masked -> 0
            p1[r] = __expf(p1[r] - m_new);
            ls += p0[r] + p1[r];
        }
        l_part = l_part * alpha + ls;            // per-lane partial
        m_prev = m_new;

        // pack P^T halves into B-frags (upper 4 bf16 = 0)
        bfrag pb0, pb1;
        ((uint2*)&pb0)[0] = make_uint2(pk2bf(p0[0], p0[1]), pk2bf(p0[2], p0[3]));
        ((uint2*)&pb0)[1] = make_uint2(0u, 0u);
        ((uint2*)&pb1)[0] = make_uint2(pk2bf(p1[0], p1[1]), pk2bf(p1[2], p1[3]));
        ((uint2*)&pb1)[1] = make_uint2(0u, 0u);

        // O^T rescale: cols = q = l15 -> alpha in-lane
        #pragma unroll
        for (int c = 0; c < 4; ++c)
            #pragma unroll
            for (int r = 0; r < 4; ++r) OT[c][r] *= alpha;

        // O^T += V^T . P^T  (A = V^T frag, upper j don't-care vs zero B)
        #pragma unroll
        for (int c = 0; c < 4; ++c) {
            bfrag va0, va1;
            ((uint2*)&va0)[0] = Vf[c * 2];     ((uint2*)&va0)[1] = Vf[c * 2];
            ((uint2*)&va1)[0] = Vf[c * 2 + 1]; ((uint2*)&va1)[1] = Vf[c * 2 + 1];
            OT[c] = __builtin_amdgcn_mfma_f32_16x16x32_bf16(va0, pb0, OT[c], 0, 0, 0);
            OT[c] = __builtin_amdgcn_mfma_f32_16x16x32_bf16(va1, pb1, OT[c], 0, 0, 0);
        }
    };

    auto step = [&](int kt, bfrag (&cK)[4], uint2 (&cV)[8],
                    bfrag (&nK)[4], uint2 (&nV)[8]) {
        if (kt + 1 < ntB) loadTile((kt + 1) * FA_BK, nK, nV);
        const int k0 = kt * FA_BK;
        if (kt < ntA)
            streamTile(k0, qwA, QA0, QA1, cK, cV, OTA, mA, lA);
        streamTile(k0, qwB, QB0, QB1, cK, cV, OTB, mB, lB);
    };

    loadTile(0, Kc, Vc);
    int kt = 0;
    while (true) {
        step(kt, Kc, Vc, Kn, Vn);
        if (++kt >= ntB) break;
        step(kt, Kn, Vn, Kc, Vc);
        if (++kt >= ntB) break;
    }

    // final l reductions (over quads) + epilogue: bf16 ctx [B,S,D]
    lA += __shfl_xor(lA, 16, 64); lA += __shfl_xor(lA, 32, 64);
    lB += __shfl_xor(lB, 16, 64); lB += __shfl_xor(lB, 32, 64);
    float invA = 1.0f / lA;       // per-lane (q = l15)
    float invB = 1.0f / lB;

    const int b = bh >> 4, hh = bh & 15;
    size_t rowA = ((size_t)b * Sdim + qwA + l15) * Ddim + hh * HDdim + quad * 4;
    size_t rowB = ((size_t)b * Sdim + qwB + l15) * Ddim + hh * HDdim + quad * 4;
    #pragma unroll
    for (int c = 0; c < 4; ++c) {
        uint2 ua = make_uint2(pk2bf(OTA[c][0] * invA, OTA[c][1] * invA),
                              pk2bf(OTA[c][2] * invA, OTA[c][3] * invA));
        uint2 ub = make_uint2(pk2bf(OTB[c][0] * invB, OTB[c][1] * invB),
                              pk2bf(OTB[c][2] * invB, OTB[c][3] * invB));
        *(uint2*)&ctx[rowA + c * 16] = ua;
        *(uint2*)&ctx[rowB + c * 16] = ub;
    }
}

// ---------------- launch ----------------
extern "C" void kernel_launch(void* const* d_in, const int* in_sizes, int n_in,
                              void* d_out, int out_size, void* d_ws, size_t ws_size,
                              hipStream_t stream)
{
    const int NX = Mdim * Ddim;
    const int NW = Ddim * Ddim;
    int xi = 0, wi[4] = {1, 3, 5, 7}, bi[4] = {2, 4, 6, 8}, nw = 0, nb = 0;
    bool sized = true;
    for (int i = 0; i < 9; ++i) {
        if (in_sizes[i] == NX) xi = i;
        else if (in_sizes[i] == NW) { if (nw < 4) wi[nw++] = i; }
        else if (in_sizes[i] == Ddim) { if (nb < 4) bi[nb++] = i; }
        else sized = false;
    }
    int iWq, iWk, iWv, iWo, ibq, ibk, ibv, ibo;
    if (!sized || xi == 0) {
        xi = 0; iWq = 1; ibq = 2; iWk = 3; ibk = 4; iWv = 5; ibv = 6; iWo = 7; ibo = 8;
    } else {
        iWk = wi[0]; iWo = wi[1]; iWq = wi[2]; iWv = wi[3];
        ibk = bi[0]; ibo = bi[1]; ibq = bi[2]; ibv = bi[3];
    }

    const float* x  = (const float*)d_in[xi];
    const float* Wq = (const float*)d_in[iWq];
    const float* bq = (const float*)d_in[ibq];
    const float* Wk = (const float*)d_in[iWk];
    const float* bk = (const float*)d_in[ibk];
    const float* Wv = (const float*)d_in[iWv];
    const float* bv = (const float*)d_in[ibv];
    const float* Wo = (const float*)d_in[iWo];
    const float* bo = (const float*)d_in[ibo];
    float* out = (float*)d_out;

    const size_t elems = (size_t)Mdim * Ddim;
    const size_t welems = (size_t)Ddim * Ddim;
    ushort_t* Qb    = (ushort_t*)d_ws;
    ushort_t* Kb    = Qb + elems;
    ushort_t* Vtb   = Kb + elems;
    ushort_t* Cb    = Vtb + elems;
    ushort_t* xb    = Cb + elems;
    ushort_t* qkvT  = xb + elems;
    ushort_t* WoT   = qkvT + 3 * welems;

    dim3 blk(256);
    cast_x<<<dim3(Mdim * Ddim / (256 * 8)), blk, 0, stream>>>(x, xb);
    wtrans<<<dim3(16, 16, 4), blk, 0, stream>>>(Wq, Wk, Wv, Wo, qkvT, WoT);

    gemm_mfma<0><<<dim3(3 * Ddim / 128, Mdim / 128), blk, 0, stream>>>(
        xb, qkvT, bq, bk, bv, Qb, Kb, Vtb, nullptr);

    flash_mfma<<<dim3(2048), dim3(64), 0, stream>>>(Qb, Kb, Vtb, Cb);

    gemm_mfma<1><<<dim3(Ddim / 128, Mdim / 128), blk, 0, stream>>>(
        Cb, WoT, bo, nullptr, nullptr, nullptr, nullptr, nullptr, out);
}